// Round 3
// baseline (1978.335 us; speedup 1.0000x reference)
//
#include <hip/hip_runtime.h>
#include <hip/hip_bf16.h>

#define NUM_USERS 100000
#define NUM_ITEMS 50000
#define N_NODES   150000
#define EMB_DIM   64
#define TEXT_DIM  384
#define N_EDGES   4800000
#define SCAN_CHUNK 2048

// ---------------- counting-sort: histogram ----------------
__global__ __launch_bounds__(256) void zero_kernel(int* __restrict__ p, int n) {
    int i = blockIdx.x * 256 + threadIdx.x;
    if (i < n) p[i] = 0;
}

__global__ __launch_bounds__(256) void hist_kernel(const int* __restrict__ erow,
                                                   int* __restrict__ counts, int n) {
    int i = blockIdx.x * 256 + threadIdx.x;
    if (i < n) atomicAdd(&counts[erow[i]], 1);
}

// ---------------- 3-pass exclusive scan over N_NODES+1 ints ----------------
__global__ __launch_bounds__(256) void scan_p1(const int* __restrict__ counts,
                                               int* __restrict__ bsums, int n) {
    __shared__ int s[256];
    int tid = threadIdx.x;
    int base = blockIdx.x * SCAN_CHUNK + tid * 8;
    int sum = 0;
#pragma unroll
    for (int j = 0; j < 8; ++j) { int idx = base + j; if (idx < n) sum += counts[idx]; }
    s[tid] = sum; __syncthreads();
    for (int off = 128; off > 0; off >>= 1) {
        if (tid < off) s[tid] += s[tid + off];
        __syncthreads();
    }
    if (tid == 0) bsums[blockIdx.x] = s[0];
}

__global__ void scan_p2(int* __restrict__ bsums, int nb) {
    if (threadIdx.x == 0 && blockIdx.x == 0) {
        int acc = 0;
        for (int i = 0; i < nb; ++i) { int v = bsums[i]; bsums[i] = acc; acc += v; }
    }
}

__global__ __launch_bounds__(256) void scan_p3(int* __restrict__ counts /*in-place -> row_start*/,
                                               const int* __restrict__ bsums,
                                               int* __restrict__ cursor, int n) {
    __shared__ int s[256];
    int tid = threadIdx.x;
    int base = blockIdx.x * SCAN_CHUNK + tid * 8;
    int v[8]; int sum = 0;
#pragma unroll
    for (int j = 0; j < 8; ++j) { int idx = base + j; v[j] = (idx < n) ? counts[idx] : 0; sum += v[j]; }
    s[tid] = sum; __syncthreads();
    // Hillis-Steele inclusive scan over 256 thread sums
    for (int off = 1; off < 256; off <<= 1) {
        int t = (tid >= off) ? s[tid - off] : 0;
        __syncthreads();
        s[tid] += t;
        __syncthreads();
    }
    int run = bsums[blockIdx.x] + (s[tid] - sum);   // exclusive prefix for this thread
#pragma unroll
    for (int j = 0; j < 8; ++j) {
        int idx = base + j;
        if (idx < n) {
            counts[idx] = run;
            if (idx < N_NODES) cursor[idx] = run;
        }
        run += v[j];
    }
}

// ---------------- counting-sort: scatter ----------------
__global__ __launch_bounds__(256) void scatter_kernel(const int* __restrict__ erow,
                                                      const int* __restrict__ ecol,
                                                      const float* __restrict__ eval,
                                                      int* __restrict__ cursor,
                                                      int* __restrict__ scol,
                                                      float* __restrict__ sval, int n) {
    int i = blockIdx.x * 256 + threadIdx.x;
    if (i < n) {
        int r = erow[i];
        int pos = atomicAdd(&cursor[r], 1);
        scol[pos] = ecol[i];
        sval[pos] = eval[i];
    }
}

// ---------------- init: text GEMM + assemble X = [emb_id | emb_text] ----------------
#define ROWS_A 16
__global__ __launch_bounds__(256) void init_kernel(const float* __restrict__ text,
                                                   const float* __restrict__ Wt,
                                                   const float* __restrict__ bt,
                                                   const float* __restrict__ uemb,
                                                   const float* __restrict__ iemb,
                                                   float* __restrict__ X) {
    __shared__ float ts[ROWS_A][TEXT_DIM];   // 24.5 KB
    int t = threadIdx.x;
    int r0 = blockIdx.x * ROWS_A;
    const float4* src = (const float4*)(text + (size_t)r0 * TEXT_DIM);
    float4* dst = (float4*)&ts[0][0];
#pragma unroll
    for (int j = 0; j < 6; ++j) dst[t + j * 256] = src[t + j * 256];
    __syncthreads();
    int c = t & 63, w = t >> 6;
    float bias = bt[c];
    float acc[4];
#pragma unroll
    for (int r = 0; r < 4; ++r) acc[r] = bias;
#pragma unroll 4
    for (int k = 0; k < TEXT_DIM; ++k) {
        float wv = Wt[k * 64 + c];           // coalesced, L2-resident (96 KB)
#pragma unroll
        for (int r = 0; r < 4; ++r) acc[r] += wv * ts[w * 4 + r][k];  // LDS broadcast
    }
#pragma unroll
    for (int r = 0; r < 4; ++r) {
        int row = r0 + w * 4 + r;
        float idv = (row < NUM_USERS) ? uemb[(size_t)row * 64 + c]
                                      : iemb[(size_t)(row - NUM_USERS) * 64 + c];
        X[(size_t)row * 128 + c] = idv;
        X[(size_t)row * 128 + 64 + c] = acc[r];
    }
}

// ---------------- CSR SpMM: one wave per row, register accumulate ----------------
// LAYER==1: Y[row] = spmm(X)[row]           (pure, X untouched)
// LAYER==2: X[row] += Y[row] + spmm(Y)[row] (X becomes h0+h1+h2)
template <int LAYER>
__global__ __launch_bounds__(256) void spmm_kernel(const float* __restrict__ src,
                                                   float* __restrict__ Y,
                                                   float* __restrict__ X,
                                                   const int* __restrict__ rstart,
                                                   const int* __restrict__ scol,
                                                   const float* __restrict__ sval) {
    int wave = threadIdx.x >> 6;
    int lane = threadIdx.x & 63;
    int row = blockIdx.x * 4 + wave;
    if (row >= N_NODES) return;
    int beg = rstart[row], end = rstart[row + 1];
    float a0 = 0.f, a1 = 0.f;
    for (int b = beg; b < end; b += 64) {
        int e = b + lane;
        int cc = 0; float vv = 0.f;
        if (e < end) { cc = scol[e]; vv = sval[e]; }
        int m = min(64, end - b);
        for (int j = 0; j < m; ++j) {
            int   cj = __shfl(cc, j);
            float vj = __shfl(vv, j);
            a0 += vj * src[(size_t)cj * 128 + lane];
            a1 += vj * src[(size_t)cj * 128 + 64 + lane];
        }
    }
    size_t o = (size_t)row * 128;
    if (LAYER == 1) {
        Y[o + lane] = a0;
        Y[o + 64 + lane] = a1;
    } else {
        X[o + lane]      += src[o + lane] + a0;       // src == Y
        X[o + 64 + lane] += src[o + 64 + lane] + a1;
    }
}

// ---------------- fuse: gate GEMM + output ----------------
__global__ __launch_bounds__(256) void fuse_kernel(const float* __restrict__ X,
                                                   const float* __restrict__ Wf,
                                                   const float* __restrict__ bf,
                                                   const int* __restrict__ tmask,   // bool uploaded as int32
                                                   const float* __restrict__ tamp,
                                                   float* __restrict__ out) {
    __shared__ float wfs[128 * 64];  // 32 KB
    int t = threadIdx.x, c = t & 63, w = t >> 6;
    for (int j = t; j < 2048; j += 256) ((float4*)wfs)[j] = ((const float4*)Wf)[j];
    float bias = bf[c];
    float amp = 1.f + 1.f / (1.f + __expf(-tamp[0]));
    __syncthreads();
    const float inv3 = 1.f / 3.f;
    int rowbase = blockIdx.x * 256 + w * 64;
    for (int i = 0; i < 64; ++i) {
        int row = rowbase + i;
        if (row >= N_NODES) break;   // no barriers below: safe
        size_t o = (size_t)row * 128;
        float s1 = (tmask[row] != 0) ? inv3 * amp : inv3;
        float accA = 0.f, accB = 0.f;
#pragma unroll 8
        for (int k = 0; k < 64; ++k) accA += X[o + k] * wfs[k * 64 + c];
#pragma unroll 8
        for (int k = 0; k < 64; ++k) accB += X[o + 64 + k] * wfs[(64 + k) * 64 + c];
        float z = accA * inv3 + accB * s1 + bias;
        float g = 1.f / (1.f + __expf(-z));
        float idf = X[o + c] * inv3;
        float txf = X[o + 64 + c] * s1;
        out[(size_t)row * 64 + c] = g * idf + (1.f - g) * txf;
    }
}

extern "C" void kernel_launch(void* const* d_in, const int* in_sizes, int n_in,
                              void* d_out, int out_size, void* d_ws, size_t ws_size,
                              hipStream_t stream) {
    const float* text = (const float*)d_in[0];
    const int*   erow = (const int*)d_in[1];
    const int*   ecol = (const int*)d_in[2];
    const float* eval = (const float*)d_in[3];
    const int*   tmask= (const int*)d_in[4];    // bool -> int32 per harness convention
    const float* uemb = (const float*)d_in[5];
    const float* iemb = (const float*)d_in[6];
    const float* Wt   = (const float*)d_in[7];
    const float* bt   = (const float*)d_in[8];
    const float* Wf   = (const float*)d_in[9];
    const float* bf   = (const float*)d_in[10];
    const float* tamp = (const float*)d_in[11];
    float* out = (float*)d_out;

    // Workspace layout (all offsets 256 B aligned); total = 193,200,640 B.
    const size_t OFF_Y      = 76800000;
    const size_t OFF_SCOL   = 153600000;
    const size_t OFF_SVAL   = 172800000;
    const size_t OFF_RSTART = 192000000;
    const size_t OFF_CURSOR = 192600064;
    const size_t OFF_BSUMS  = 193200128;
    const size_t WS_NEEDED  = OFF_BSUMS + 512;
    if (ws_size < WS_NEEDED) {
        return;  // insufficient scratch: fail cleanly instead of OOB
    }

    char* ws = (char*)d_ws;
    float* X      = (float*)(ws);
    float* Y      = (float*)(ws + OFF_Y);
    int*   scol   = (int*)  (ws + OFF_SCOL);
    float* sval   = (float*)(ws + OFF_SVAL);
    int*   rstart = (int*)  (ws + OFF_RSTART);
    int*   cursor = (int*)  (ws + OFF_CURSOR);
    int*   bsums  = (int*)  (ws + OFF_BSUMS);

    const int nb = (N_NODES + 1 + SCAN_CHUNK - 1) / SCAN_CHUNK;   // 74

    // 1) build CSR by counting sort
    zero_kernel<<<(N_NODES + 1 + 255) / 256, 256, 0, stream>>>(rstart, N_NODES + 1);
    hist_kernel<<<N_EDGES / 256, 256, 0, stream>>>(erow, rstart, N_EDGES);
    scan_p1<<<nb, 256, 0, stream>>>(rstart, bsums, N_NODES + 1);
    scan_p2<<<1, 64, 0, stream>>>(bsums, nb);
    scan_p3<<<nb, 256, 0, stream>>>(rstart, bsums, cursor, N_NODES + 1);
    scatter_kernel<<<N_EDGES / 256, 256, 0, stream>>>(erow, ecol, eval, cursor, scol, sval, N_EDGES);

    // 2) X = [emb_id | text @ W + b]
    init_kernel<<<N_NODES / ROWS_A, 256, 0, stream>>>(text, Wt, bt, uemb, iemb, X);

    // 3) two propagation layers (Y = h1; X accumulates h0+h1+h2)
    spmm_kernel<1><<<(N_NODES + 3) / 4, 256, 0, stream>>>(X, Y, X, rstart, scol, sval);
    spmm_kernel<2><<<(N_NODES + 3) / 4, 256, 0, stream>>>(Y, Y, X, rstart, scol, sval);

    // 4) gate + fuse -> out
    fuse_kernel<<<(N_NODES + 255) / 256, 256, 0, stream>>>(X, Wf, bf, tmask, tamp, out);
}

// Round 4
// 1879.005 us; speedup vs baseline: 1.0529x; 1.0529x over previous
//
#include <hip/hip_runtime.h>
#include <hip/hip_bf16.h>

#define NUM_USERS 100000
#define NUM_ITEMS 50000
#define N_NODES   150000
#define EMB_DIM   64
#define TEXT_DIM  384
#define N_EDGES   4800000
#define SCAN_CHUNK 2048

// ---------------- counting-sort: histogram ----------------
__global__ __launch_bounds__(256) void zero_kernel(int* __restrict__ p, int n) {
    int i = blockIdx.x * 256 + threadIdx.x;
    if (i < n) p[i] = 0;
}

__global__ __launch_bounds__(256) void hist_kernel(const int* __restrict__ erow,
                                                   int* __restrict__ counts, int n) {
    int i = blockIdx.x * 256 + threadIdx.x;
    if (i < n) atomicAdd(&counts[erow[i]], 1);
}

// ---------------- 3-pass exclusive scan over N_NODES+1 ints ----------------
__global__ __launch_bounds__(256) void scan_p1(const int* __restrict__ counts,
                                               int* __restrict__ bsums, int n) {
    __shared__ int s[256];
    int tid = threadIdx.x;
    int base = blockIdx.x * SCAN_CHUNK + tid * 8;
    int sum = 0;
#pragma unroll
    for (int j = 0; j < 8; ++j) { int idx = base + j; if (idx < n) sum += counts[idx]; }
    s[tid] = sum; __syncthreads();
    for (int off = 128; off > 0; off >>= 1) {
        if (tid < off) s[tid] += s[tid + off];
        __syncthreads();
    }
    if (tid == 0) bsums[blockIdx.x] = s[0];
}

__global__ void scan_p2(int* __restrict__ bsums, int nb) {
    if (threadIdx.x == 0 && blockIdx.x == 0) {
        int acc = 0;
        for (int i = 0; i < nb; ++i) { int v = bsums[i]; bsums[i] = acc; acc += v; }
    }
}

__global__ __launch_bounds__(256) void scan_p3(int* __restrict__ counts /*in-place -> row_start*/,
                                               const int* __restrict__ bsums,
                                               int* __restrict__ cursor, int n) {
    __shared__ int s[256];
    int tid = threadIdx.x;
    int base = blockIdx.x * SCAN_CHUNK + tid * 8;
    int v[8]; int sum = 0;
#pragma unroll
    for (int j = 0; j < 8; ++j) { int idx = base + j; v[j] = (idx < n) ? counts[idx] : 0; sum += v[j]; }
    s[tid] = sum; __syncthreads();
    // Hillis-Steele inclusive scan over 256 thread sums
    for (int off = 1; off < 256; off <<= 1) {
        int t = (tid >= off) ? s[tid - off] : 0;
        __syncthreads();
        s[tid] += t;
        __syncthreads();
    }
    int run = bsums[blockIdx.x] + (s[tid] - sum);   // exclusive prefix for this thread
#pragma unroll
    for (int j = 0; j < 8; ++j) {
        int idx = base + j;
        if (idx < n) {
            counts[idx] = run;
            if (idx < N_NODES) cursor[idx] = run;
        }
        run += v[j];
    }
}

// ---------------- counting-sort: scatter (packed 8B payload) ----------------
__global__ __launch_bounds__(256) void scatter_kernel(const int* __restrict__ erow,
                                                      const int* __restrict__ ecol,
                                                      const float* __restrict__ eval,
                                                      int* __restrict__ cursor,
                                                      uint2* __restrict__ sedge, int n) {
    int i = blockIdx.x * 256 + threadIdx.x;
    if (i < n) {
        int r = erow[i];
        int pos = atomicAdd(&cursor[r], 1);
        uint2 e;
        e.x = (unsigned)ecol[i];
        e.y = __float_as_uint(eval[i]);
        sedge[pos] = e;   // single 8B store -> one line touch per edge
    }
}

// ---------------- init: text GEMM + assemble X = [emb_id | emb_text] ----------------
#define ROWS_A 16
__global__ __launch_bounds__(256) void init_kernel(const float* __restrict__ text,
                                                   const float* __restrict__ Wt,
                                                   const float* __restrict__ bt,
                                                   const float* __restrict__ uemb,
                                                   const float* __restrict__ iemb,
                                                   float* __restrict__ X) {
    __shared__ float ts[ROWS_A][TEXT_DIM];   // 24.5 KB
    int t = threadIdx.x;
    int r0 = blockIdx.x * ROWS_A;
    const float4* src = (const float4*)(text + (size_t)r0 * TEXT_DIM);
    float4* dst = (float4*)&ts[0][0];
#pragma unroll
    for (int j = 0; j < 6; ++j) dst[t + j * 256] = src[t + j * 256];
    __syncthreads();
    int c = t & 63, w = t >> 6;
    float bias = bt[c];
    float acc[4];
#pragma unroll
    for (int r = 0; r < 4; ++r) acc[r] = bias;
#pragma unroll 4
    for (int k = 0; k < TEXT_DIM; ++k) {
        float wv = Wt[k * 64 + c];           // coalesced, L2-resident (96 KB)
#pragma unroll
        for (int r = 0; r < 4; ++r) acc[r] += wv * ts[w * 4 + r][k];  // LDS broadcast
    }
#pragma unroll
    for (int r = 0; r < 4; ++r) {
        int row = r0 + w * 4 + r;
        float idv = (row < NUM_USERS) ? uemb[(size_t)row * 64 + c]
                                      : iemb[(size_t)(row - NUM_USERS) * 64 + c];
        X[(size_t)row * 128 + c] = idv;
        X[(size_t)row * 128 + 64 + c] = acc[r];
    }
}

// ---------------- CSR SpMM: one wave per row, float2 gathers ----------------
// Lane l owns features {2l, 2l+1}: one b64 wave-load covers the full 512B row.
// LAYER==1: Y[row] = spmm(X)[row]           (pure, X untouched)
// LAYER==2: X[row] += Y[row] + spmm(Y)[row] (X becomes h0+h1+h2)
template <int LAYER>
__global__ __launch_bounds__(256) void spmm_kernel(const float* __restrict__ src,
                                                   float* __restrict__ Y,
                                                   float* __restrict__ X,
                                                   const int* __restrict__ rstart,
                                                   const uint2* __restrict__ sedge) {
    int wave = threadIdx.x >> 6;
    int lane = threadIdx.x & 63;
    int row = blockIdx.x * 4 + wave;
    if (row >= N_NODES) return;
    int beg = rstart[row], end = rstart[row + 1];
    float a0 = 0.f, a1 = 0.f;
    const float2* s2 = (const float2*)src;
    for (int b = beg; b < end; b += 64) {
        int e = b + lane;
        uint2 ed = make_uint2(0u, 0u);
        if (e < end) ed = sedge[e];
        int m = min(64, end - b);
        for (int j = 0; j < m; ++j) {
            int   cj = __shfl((int)ed.x, j);
            float vj = __shfl(__uint_as_float(ed.y), j);
            float2 v = s2[(size_t)cj * 64 + lane];
            a0 += vj * v.x;
            a1 += vj * v.y;
        }
    }
    size_t o2 = (size_t)row * 64 + lane;
    if (LAYER == 1) {
        float2 r; r.x = a0; r.y = a1;
        ((float2*)Y)[o2] = r;
    } else {
        float2 xv = ((const float2*)X)[o2];
        float2 yv = s2[o2];                    // src == Y
        xv.x += yv.x + a0;
        xv.y += yv.y + a1;
        ((float2*)X)[o2] = xv;
    }
}

// ---------------- fuse: LDS-tiled gate GEMM + output ----------------
// Block: 64 rows x 64 cols, 256 threads, 4x4 register tile.
// A-tile staged with inv3 / amp scales folded in, so As[:,0:64]=id_final,
// As[:,64:128]=text_final; z = As @ Wf + bf; out = g*As[r][c]+(1-g)*As[r][64+c].
__global__ __launch_bounds__(256) void fuse_kernel(const float* __restrict__ X,
                                                   const float* __restrict__ Wf,
                                                   const float* __restrict__ bf,
                                                   const int* __restrict__ tmask,
                                                   const float* __restrict__ tamp,
                                                   float* __restrict__ out) {
    __shared__ float Xs[64][128];    // 32 KB (scaled A-tile)
    __shared__ float Wfs[128][64];   // 32 KB
    int t = threadIdx.x;
    int rowbase = blockIdx.x * 64;
    const float inv3 = 1.f / 3.f;
    float amp = 1.f + 1.f / (1.f + __expf(-tamp[0]));

    // stage Wf (8192 floats = 2048 float4)
    for (int j = t; j < 2048; j += 256) ((float4*)Wfs)[j] = ((const float4*)Wf)[j];
    // stage scaled X tile (64 rows x 32 float4)
#pragma unroll
    for (int j = 0; j < 8; ++j) {
        int f = t + j * 256;         // 0..2047
        int r = f >> 5;              // 0..63
        int q = f & 31;              // float4 col
        int row = rowbase + r;
        float4 v = make_float4(0.f, 0.f, 0.f, 0.f);
        if (row < N_NODES) {
            v = ((const float4*)X)[(size_t)row * 32 + q];
            float s = (q < 16) ? inv3 : ((tmask[row] != 0) ? inv3 * amp : inv3);
            v.x *= s; v.y *= s; v.z *= s; v.w *= s;
        }
        ((float4*)Xs)[f] = v;
    }
    __syncthreads();

    int tc = t & 15, tr = t >> 4;
    int c0 = tc * 4, r0 = tr * 4;
    float acc[4][4];
#pragma unroll
    for (int i = 0; i < 4; ++i)
#pragma unroll
        for (int j = 0; j < 4; ++j) acc[i][j] = 0.f;

    for (int k = 0; k < 128; k += 4) {
#pragma unroll
        for (int kk = 0; kk < 4; ++kk) {
            float4 wv = *(const float4*)&Wfs[k + kk][c0];
#pragma unroll
            for (int i = 0; i < 4; ++i) {
                float xv = Xs[r0 + i][k + kk];
                acc[i][0] += xv * wv.x;
                acc[i][1] += xv * wv.y;
                acc[i][2] += xv * wv.z;
                acc[i][3] += xv * wv.w;
            }
        }
    }

    float4 bq = *(const float4*)&bf[c0];
#pragma unroll
    for (int i = 0; i < 4; ++i) {
        int row = rowbase + r0 + i;
        if (row >= N_NODES) break;
        float4 idf = *(const float4*)&Xs[r0 + i][c0];
        float4 txf = *(const float4*)&Xs[r0 + i][64 + c0];
        float4 o;
        float g;
        g = 1.f / (1.f + __expf(-(acc[i][0] + bq.x))); o.x = g * idf.x + (1.f - g) * txf.x;
        g = 1.f / (1.f + __expf(-(acc[i][1] + bq.y))); o.y = g * idf.y + (1.f - g) * txf.y;
        g = 1.f / (1.f + __expf(-(acc[i][2] + bq.z))); o.z = g * idf.z + (1.f - g) * txf.z;
        g = 1.f / (1.f + __expf(-(acc[i][3] + bq.w))); o.w = g * idf.w + (1.f - g) * txf.w;
        ((float4*)out)[(size_t)row * 16 + tc] = o;
    }
}

extern "C" void kernel_launch(void* const* d_in, const int* in_sizes, int n_in,
                              void* d_out, int out_size, void* d_ws, size_t ws_size,
                              hipStream_t stream) {
    const float* text = (const float*)d_in[0];
    const int*   erow = (const int*)d_in[1];
    const int*   ecol = (const int*)d_in[2];
    const float* eval = (const float*)d_in[3];
    const int*   tmask= (const int*)d_in[4];    // bool -> int32 per harness convention
    const float* uemb = (const float*)d_in[5];
    const float* iemb = (const float*)d_in[6];
    const float* Wt   = (const float*)d_in[7];
    const float* bt   = (const float*)d_in[8];
    const float* Wf   = (const float*)d_in[9];
    const float* bf   = (const float*)d_in[10];
    const float* tamp = (const float*)d_in[11];
    float* out = (float*)d_out;

    // Workspace layout (256 B aligned); total = 193,200,640 B.
    const size_t OFF_Y      = 76800000;     // X: [N,128] f32 at 0
    const size_t OFF_SEDGE  = 153600000;    // Y: [N,128] f32
    const size_t OFF_RSTART = 192000000;    // sedge: E x uint2 (38.4 MB)
    const size_t OFF_CURSOR = 192600064;
    const size_t OFF_BSUMS  = 193200128;
    const size_t WS_NEEDED  = OFF_BSUMS + 512;
    if (ws_size < WS_NEEDED) {
        return;  // insufficient scratch: fail cleanly instead of OOB
    }

    char* ws = (char*)d_ws;
    float* X      = (float*)(ws);
    float* Y      = (float*)(ws + OFF_Y);
    uint2* sedge  = (uint2*)(ws + OFF_SEDGE);
    int*   rstart = (int*)  (ws + OFF_RSTART);
    int*   cursor = (int*)  (ws + OFF_CURSOR);
    int*   bsums  = (int*)  (ws + OFF_BSUMS);

    const int nb = (N_NODES + 1 + SCAN_CHUNK - 1) / SCAN_CHUNK;   // 74

    // 1) build CSR by counting sort
    zero_kernel<<<(N_NODES + 1 + 255) / 256, 256, 0, stream>>>(rstart, N_NODES + 1);
    hist_kernel<<<N_EDGES / 256, 256, 0, stream>>>(erow, rstart, N_EDGES);
    scan_p1<<<nb, 256, 0, stream>>>(rstart, bsums, N_NODES + 1);
    scan_p2<<<1, 64, 0, stream>>>(bsums, nb);
    scan_p3<<<nb, 256, 0, stream>>>(rstart, bsums, cursor, N_NODES + 1);
    scatter_kernel<<<N_EDGES / 256, 256, 0, stream>>>(erow, ecol, eval, cursor, sedge, N_EDGES);

    // 2) X = [emb_id | text @ W + b]
    init_kernel<<<N_NODES / ROWS_A, 256, 0, stream>>>(text, Wt, bt, uemb, iemb, X);

    // 3) two propagation layers (Y = h1; X accumulates h0+h1+h2)
    spmm_kernel<1><<<(N_NODES + 3) / 4, 256, 0, stream>>>(X, Y, X, rstart, sedge);
    spmm_kernel<2><<<(N_NODES + 3) / 4, 256, 0, stream>>>(Y, Y, X, rstart, sedge);

    // 4) gate + fuse -> out
    fuse_kernel<<<(N_NODES + 63) / 64, 256, 0, stream>>>(X, Wf, bf, tmask, tamp, out);
}